// Round 24
// baseline (165.223 us; speedup 1.0000x reference)
//
#include <hip/hip_runtime.h>
#include <math.h>

#define N_NODES  100000
#define N_EDGES  1600000
#define N_GRAPHS 1000
#define F_IN     9
#define HID      64
#define NBUCK    196    // ceil(N_NODES / 512), bucket = dst >> 9
#define BCAP     12288  // fixed capacity per bucket (mean 8163, +45 sigma)
#define CHUNK    4096   // edges per partition block
#define NZERO    128200 // words to zero (poolA + poolH + gcur)
#define NPB      32     // nodes per agg_l1 block

typedef unsigned int uint32;
typedef float v2f __attribute__((ext_vector_type(2)));

// ---------------------------------------------------------------------------
// Workspace layout (4-byte words):
//   [0,        64000)    poolA  (float) -- zeroed (graph-sum of mean-agg(h1))
//   [64000,    128000)   poolH  (float) -- zeroed (graph-sum of h1)
//   [128000,   128196)   gcur   (int)   -- zeroed (bucket fill cursors)
//   ZERO region = [0, 128200)  (custom zero_kernel; the ~44us fillBuffer in
//   the profile is the HARNESS's one-time d_ws poison, not in the replay path)
//   [128200,   328200)   rowcnt (int2 per node: {col start, degree})
//   [328200,   2736648)  col    (int, NBUCK*BCAP)
//   [2736648,  5145096)  ebuf   (packed int: src | ldst<<17, NBUCK*BCAP)
//   [5145096,  5545096)  x8b    (fp8 e4m3, N*16 feats = 4 words/node)
//   [5545096,  7145096)  h1b    (fp8 e4m3, row-major, N*64 feats = 16 words/node)
// Total 7.15M words = 28.6 MB.
// ---------------------------------------------------------------------------

// HW fp8 e4m3 converters (gfx950 OCP e4m3fn; roundtrip-consistent)
__device__ __forceinline__ uint32 pk_lo(float a, float b, uint32 old) {
    return (uint32)__builtin_amdgcn_cvt_pk_fp8_f32(a, b, (int)old, false);
}
__device__ __forceinline__ uint32 pk_hi(float a, float b, uint32 old) {
    return (uint32)__builtin_amdgcn_cvt_pk_fp8_f32(a, b, (int)old, true);
}
__device__ __forceinline__ float bfl(uint32 w) { return __uint_as_float(w << 16); }
__device__ __forceinline__ float bfh(uint32 w) { return __uint_as_float(w & 0xffff0000u); }
__device__ __forceinline__ uint32 f2bf1(float f) {
    uint32 u = __float_as_uint(f);
    u += 0x7fffu + ((u >> 16) & 1u);           // round-to-nearest-even
    return u >> 16;
}
__device__ __forceinline__ uint32 bfpair(float lo, float hi) {
    return f2bf1(lo) | (f2bf1(hi) << 16);
}

// accumulate two fp8 rows (8 feats of each) into 4 v2f accumulators
__device__ __forceinline__ void acc2(const uint32* __restrict__ hb, int c0, int c1,
                                     v2f& a0, v2f& a1, v2f& a2, v2f& a3) {
    uint2 d0 = *reinterpret_cast<const uint2*>(hb + (size_t)c0 * 16);
    uint2 d1 = *reinterpret_cast<const uint2*>(hb + (size_t)c1 * 16);
    a0 += __builtin_amdgcn_cvt_pk_f32_fp8((int)d0.x, false);
    a1 += __builtin_amdgcn_cvt_pk_f32_fp8((int)d0.x, true);
    a2 += __builtin_amdgcn_cvt_pk_f32_fp8((int)d0.y, false);
    a3 += __builtin_amdgcn_cvt_pk_f32_fp8((int)d0.y, true);
    a0 += __builtin_amdgcn_cvt_pk_f32_fp8((int)d1.x, false);
    a1 += __builtin_amdgcn_cvt_pk_f32_fp8((int)d1.x, true);
    a2 += __builtin_amdgcn_cvt_pk_f32_fp8((int)d1.y, false);
    a3 += __builtin_amdgcn_cvt_pk_f32_fp8((int)d1.y, true);
}
__device__ __forceinline__ void acc1(const uint32* __restrict__ hb, int c0,
                                     v2f& a0, v2f& a1, v2f& a2, v2f& a3) {
    uint2 d0 = *reinterpret_cast<const uint2*>(hb + (size_t)c0 * 16);
    a0 += __builtin_amdgcn_cvt_pk_f32_fp8((int)d0.x, false);
    a1 += __builtin_amdgcn_cvt_pk_f32_fp8((int)d0.x, true);
    a2 += __builtin_amdgcn_cvt_pk_f32_fp8((int)d0.y, false);
    a3 += __builtin_amdgcn_cvt_pk_f32_fp8((int)d0.y, true);
}

// K0: zero the accumulator region
__global__ __launch_bounds__(256) void zero_kernel(float4* __restrict__ ws) {
    int i = blockIdx.x * 256 + threadIdx.x;          // 126 blocks x 256 x 4 words
    if (i * 4 < NZERO)
        ws[i] = make_float4(0.f, 0.f, 0.f, 0.f);
}

// K1: encode x -> x8b (fp8) AND fixed-capacity bucket partition (packed entries)
__global__ __launch_bounds__(256) void pad_part_kernel(const float* __restrict__ x,
                                                       const int* __restrict__ ei,
                                                       int* __restrict__ gcur,
                                                       int* __restrict__ ebuf,
                                                       uint32* __restrict__ x8b) {
    __shared__ int lcnt[NBUCK], lbase[NBUCK];
    int tid = threadIdx.x;

    // --- encode phase: one node per thread (391*256 = 100096 >= N) ---
    int n = blockIdx.x * 256 + tid;
    if (n < N_NODES) {
        uint32 w[4];
        #pragma unroll
        for (int p = 0; p < 4; ++p) {
            float v0 = (4 * p + 0 < F_IN) ? x[(size_t)n * F_IN + 4 * p + 0] : 0.0f;
            float v1 = (4 * p + 1 < F_IN) ? x[(size_t)n * F_IN + 4 * p + 1] : 0.0f;
            float v2 = (4 * p + 2 < F_IN) ? x[(size_t)n * F_IN + 4 * p + 2] : 0.0f;
            float v3 = (4 * p + 3 < F_IN) ? x[(size_t)n * F_IN + 4 * p + 3] : 0.0f;
            w[p] = pk_hi(v2, v3, pk_lo(v0, v1, 0u));
        }
        *reinterpret_cast<uint4*>(&x8b[(size_t)n * 4]) =
            make_uint4(w[0], w[1], w[2], w[3]);
    }

    // --- partition phase: block-aggregated reservation into fixed buckets ---
    for (int i = tid; i < NBUCK; i += 256) lcnt[i] = 0;
    __syncthreads();
    int e0 = blockIdx.x * CHUNK;
    int e1 = e0 + CHUNK; if (e1 > N_EDGES) e1 = N_EDGES;
    for (int e = e0 + tid; e < e1; e += 256)
        atomicAdd(&lcnt[ei[N_EDGES + e] >> 9], 1);
    __syncthreads();
    for (int i = tid; i < NBUCK; i += 256)
        lbase[i] = atomicAdd(&gcur[i], lcnt[i]);
    __syncthreads();
    for (int i = tid; i < NBUCK; i += 256) lcnt[i] = 0;
    __syncthreads();
    for (int e = e0 + tid; e < e1; e += 256) {
        int src = ei[e];
        int dst = ei[N_EDGES + e];
        int b = dst >> 9;
        int pos = lbase[b] + atomicAdd(&lcnt[b], 1);
        if (pos < BCAP)
            ebuf[(size_t)b * BCAP + pos] = src | ((dst & 511) << 17);
    }
}

// K2: per-bucket CSR build (512 nodes/bucket, 1024 threads), count+scan+place
__global__ __launch_bounds__(1024) void build_csr_kernel(const int* __restrict__ ebuf,
                                                         const int* __restrict__ gcur,
                                                         int2* __restrict__ rowcnt,
                                                         int* __restrict__ col) {
    __shared__ int cnt[512];
    __shared__ int cur[512];
    __shared__ int wsum[8];
    int b = blockIdx.x;
    int n0 = b << 9;
    int tid = threadIdx.x;
    int ec = gcur[b]; if (ec > BCAP) ec = BCAP;
    size_t base = (size_t)b * BCAP;
    if (tid < 512) cnt[tid] = 0;
    __syncthreads();
    for (int e = tid; e < ec; e += 1024)
        atomicAdd(&cnt[(uint32)ebuf[base + e] >> 17], 1);
    __syncthreads();
    int v = 0, s = 0;
    int lane = tid & 63, wid = tid >> 6;
    if (tid < 512) {                     // waves 0..7 scan the 512 counts
        v = cnt[tid];
        s = v;
        #pragma unroll
        for (int off = 1; off < 64; off <<= 1) {
            int u = __shfl_up(s, off, 64);
            if (lane >= off) s += u;
        }
        if (lane == 63) wsum[wid] = s;
    }
    __syncthreads();
    if (tid < 512) {
        int add = 0;
        for (int w = 0; w < wid; ++w) add += wsum[w];
        int off_ex = s - v + add;        // exclusive scan within bucket
        int n = n0 + tid;
        if (n < N_NODES) rowcnt[n] = make_int2((int)base + off_ex, v);
        cur[tid] = off_ex;
    }
    __syncthreads();
    for (int e = tid; e < ec; e += 1024) {
        int pv = ebuf[base + e];
        int pos = atomicAdd(&cur[(uint32)pv >> 17], 1);
        col[base + pos] = pv & 0x1FFFF;
    }
}

// K3: fused layer-1 aggregation + dense + poolH. 32 nodes/block, 3125 blocks.
__global__ __launch_bounds__(256) void agg_l1_kernel(const float* __restrict__ x,
                                                     const uint32* __restrict__ x8b,
                                                     const int2* __restrict__ rowcnt,
                                                     const int* __restrict__ col,
                                                     const float* __restrict__ Wl1,
                                                     const float* __restrict__ Wr1,
                                                     const float* __restrict__ b1,
                                                     const int* __restrict__ batch,
                                                     uint32* __restrict__ h1b,
                                                     float* __restrict__ poolH) {
    __shared__ float  w1s[F_IN * 128];   // [f][ Wl1 | Wr1 ]
    __shared__ float  bs[HID];
    __shared__ float  ss[NPB * 20];      // mean-agg tile
    __shared__ float  xs[NPB * 10];      // x tile (f32, exact)
    __shared__ uint32 hsp[NPB * 33];     // h1 rows, bf16-packed
    int tid = threadIdx.x;
    int n0 = blockIdx.x * NPB;           // 3125 * 32 = 100000 exactly
    for (int i = tid; i < F_IN * HID; i += 256) {
        int f = i >> 6, j = i & 63;
        w1s[f * 128 + j]      = Wl1[i];
        w1s[f * 128 + 64 + j] = Wr1[i];
    }
    if (tid < HID) bs[tid] = b1[tid];
    for (int i = tid; i < NPB * F_IN; i += 256) {
        int r = i / F_IN, f = i - r * F_IN;
        xs[r * 10 + f] = x[(size_t)(n0 + r) * F_IN + f];
    }

    // gather phase: node r = tid>>3; slot s = (tid>>2)&1; dword q = tid&3
    {
        int r = tid >> 3, s = (tid >> 2) & 1, q = tid & 3;
        int2 rc = rowcnt[n0 + r];
        int deg = rc.y;
        v2f a01 = {0.f, 0.f}, a23 = {0.f, 0.f};
        int i = s;
        for (; i + 6 < deg; i += 8) {    // 4 edges of this slot in flight
            int c0 = col[rc.x + i];
            int c1 = col[rc.x + i + 2];
            int c2 = col[rc.x + i + 4];
            int c3 = col[rc.x + i + 6];
            uint32 d0 = x8b[(size_t)c0 * 4 + q];
            uint32 d1 = x8b[(size_t)c1 * 4 + q];
            uint32 d2 = x8b[(size_t)c2 * 4 + q];
            uint32 d3 = x8b[(size_t)c3 * 4 + q];
            a01 += __builtin_amdgcn_cvt_pk_f32_fp8((int)d0, false);
            a23 += __builtin_amdgcn_cvt_pk_f32_fp8((int)d0, true);
            a01 += __builtin_amdgcn_cvt_pk_f32_fp8((int)d1, false);
            a23 += __builtin_amdgcn_cvt_pk_f32_fp8((int)d1, true);
            a01 += __builtin_amdgcn_cvt_pk_f32_fp8((int)d2, false);
            a23 += __builtin_amdgcn_cvt_pk_f32_fp8((int)d2, true);
            a01 += __builtin_amdgcn_cvt_pk_f32_fp8((int)d3, false);
            a23 += __builtin_amdgcn_cvt_pk_f32_fp8((int)d3, true);
        }
        for (; i < deg; i += 2) {
            uint32 d0 = x8b[(size_t)col[rc.x + i] * 4 + q];
            a01 += __builtin_amdgcn_cvt_pk_f32_fp8((int)d0, false);
            a23 += __builtin_amdgcn_cvt_pk_f32_fp8((int)d0, true);
        }
        float r4[4] = {a01[0], a01[1], a23[0], a23[1]};
        #pragma unroll
        for (int k = 0; k < 4; ++k)      // combine the 2 slots (lane bit 2)
            r4[k] += __shfl_xor(r4[k], 4, 64);
        if (s == 0) {
            float inv = 1.0f / fmaxf((float)deg, 1.0f);
            *reinterpret_cast<float4*>(&ss[r * 20 + q * 4]) =
                make_float4(r4[0] * inv, r4[1] * inv, r4[2] * inv, r4[3] * inv);
        }
    }
    __syncthreads();

    // dense phase: node r = tid>>3, col-group cg = tid&7 (8 feats each)
    int r = tid >> 3, cg = tid & 7, k0 = cg * 8;
    float h[8];
    #pragma unroll
    for (int kk = 0; kk < 8; ++kk) {
        int k = k0 + kk;
        float v = bs[k];
        #pragma unroll
        for (int f = 0; f < F_IN; ++f)
            v += ss[r * 20 + f] * w1s[f * 128 + k]
               + xs[r * 10 + f] * w1s[f * 128 + 64 + k];
        h[kk] = fmaxf(v, 0.0f);
    }
    int n = n0 + r;
    {   // fp8 encode: 8 feats -> 2 words
        uint32 w0 = pk_hi(h[2], h[3], pk_lo(h[0], h[1], 0u));
        uint32 w1 = pk_hi(h[6], h[7], pk_lo(h[4], h[5], 0u));
        *reinterpret_cast<uint2*>(&h1b[(size_t)n * 16 + cg * 2]) =
            make_uint2(w0, w1);
    }
    {   // bf16-pack into hsp for the pool tail
        hsp[r * 33 + cg * 4 + 0] = bfpair(h[0], h[1]);
        hsp[r * 33 + cg * 4 + 1] = bfpair(h[2], h[3]);
        hsp[r * 33 + cg * 4 + 2] = bfpair(h[4], h[5]);
        hsp[r * 33 + cg * 4 + 3] = bfpair(h[6], h[7]);
    }
    __syncthreads();
    if (tid < HID) {                     // grouped poolH atomics (batch sorted)
        int j = tid;
        int wsel = j >> 1;
        bool hi = (j & 1) != 0;
        int cur = batch[n0];
        uint32 w0 = hsp[wsel];
        float v = hi ? bfh(w0) : bfl(w0);
        for (int rr = 1; rr < NPB; ++rr) {
            int g = batch[n0 + rr];
            uint32 wr = hsp[rr * 33 + wsel];
            float val = hi ? bfh(wr) : bfl(wr);
            if (g == cur) v += val;
            else { atomicAdd(&poolH[cur * HID + j], v); cur = g; v = val; }
        }
        atomicAdd(&poolH[cur * HID + j], v);
    }
}

// K4: layer-2 gather, 4 interleaved nodes per wave (independent chains, 8 rows
// in flight). block = 4 waves = 16 nodes; 6250 blocks; grouped pool atomics.
__global__ __launch_bounds__(256) void gather2_kernel(const uint32* __restrict__ h1b,
                                                      const int2* __restrict__ rowcnt,
                                                      const int* __restrict__ col,
                                                      const int* __restrict__ batch,
                                                      float* __restrict__ poolA) {
    __shared__ float sh[16][HID];
    int w = threadIdx.x >> 6;
    int lane = threadIdx.x & 63;
    int slot = lane >> 3;                // 8 edge slots
    int grp  = lane & 7;                 // 8 feature groups x 8 fp8
    int base = blockIdx.x * 16;          // 6250 * 16 = 100000 exactly
    int nA = base + w * 4;
    int2 rcA = rowcnt[nA];
    int2 rcB = rowcnt[nA + 1];
    int2 rcC = rowcnt[nA + 2];
    int2 rcD = rowcnt[nA + 3];
    const uint32* hb = h1b + grp * 2;
    v2f aA0 = {0.f,0.f}, aA1 = {0.f,0.f}, aA2 = {0.f,0.f}, aA3 = {0.f,0.f};
    v2f aB0 = {0.f,0.f}, aB1 = {0.f,0.f}, aB2 = {0.f,0.f}, aB3 = {0.f,0.f};
    v2f aC0 = {0.f,0.f}, aC1 = {0.f,0.f}, aC2 = {0.f,0.f}, aC3 = {0.f,0.f};
    v2f aD0 = {0.f,0.f}, aD1 = {0.f,0.f}, aD2 = {0.f,0.f}, aD3 = {0.f,0.f};
    int iA = rcA.x + slot, endA = rcA.x + rcA.y;
    int iB = rcB.x + slot, endB = rcB.x + rcB.y;
    int iC = rcC.x + slot, endC = rcC.x + rcC.y;
    int iD = rcD.x + slot, endD = rcD.x + rcD.y;
    // fused main loop: 4 independent chains, 8 rows in flight
    while (iA + 8 < endA && iB + 8 < endB && iC + 8 < endC && iD + 8 < endD) {
        int cA0 = col[iA], cA1 = col[iA + 8];
        int cB0 = col[iB], cB1 = col[iB + 8];
        int cC0 = col[iC], cC1 = col[iC + 8];
        int cD0 = col[iD], cD1 = col[iD + 8];
        acc2(hb, cA0, cA1, aA0, aA1, aA2, aA3);
        acc2(hb, cB0, cB1, aB0, aB1, aB2, aB3);
        acc2(hb, cC0, cC1, aC0, aC1, aC2, aC3);
        acc2(hb, cD0, cD1, aD0, aD1, aD2, aD3);
        iA += 16; iB += 16; iC += 16; iD += 16;
    }
    // per-node drains (2 rows in flight each)
    for (; iA + 8 < endA; iA += 16) { int c0 = col[iA], c1 = col[iA + 8];
                                      acc2(hb, c0, c1, aA0, aA1, aA2, aA3); }
    if (iA < endA) acc1(hb, col[iA], aA0, aA1, aA2, aA3);
    for (; iB + 8 < endB; iB += 16) { int c0 = col[iB], c1 = col[iB + 8];
                                      acc2(hb, c0, c1, aB0, aB1, aB2, aB3); }
    if (iB < endB) acc1(hb, col[iB], aB0, aB1, aB2, aB3);
    for (; iC + 8 < endC; iC += 16) { int c0 = col[iC], c1 = col[iC + 8];
                                      acc2(hb, c0, c1, aC0, aC1, aC2, aC3); }
    if (iC < endC) acc1(hb, col[iC], aC0, aC1, aC2, aC3);
    for (; iD + 8 < endD; iD += 16) { int c0 = col[iD], c1 = col[iD + 8];
                                      acc2(hb, c0, c1, aD0, aD1, aD2, aD3); }
    if (iD < endD) acc1(hb, col[iD], aD0, aD1, aD2, aD3);

    float rA[8] = {aA0[0], aA0[1], aA1[0], aA1[1], aA2[0], aA2[1], aA3[0], aA3[1]};
    float rB[8] = {aB0[0], aB0[1], aB1[0], aB1[1], aB2[0], aB2[1], aB3[0], aB3[1]};
    float rC[8] = {aC0[0], aC0[1], aC1[0], aC1[1], aC2[0], aC2[1], aC3[0], aC3[1]};
    float rD[8] = {aD0[0], aD0[1], aD1[0], aD1[1], aD2[0], aD2[1], aD3[0], aD3[1]};
    float invA = 1.0f / fmaxf((float)rcA.y, 1.0f);
    float invB = 1.0f / fmaxf((float)rcB.y, 1.0f);
    float invC = 1.0f / fmaxf((float)rcC.y, 1.0f);
    float invD = 1.0f / fmaxf((float)rcD.y, 1.0f);
    #pragma unroll
    for (int k = 0; k < 8; ++k) {        // reduce across 8 slots (lane bits 3..5)
        rA[k] += __shfl_xor(rA[k], 8, 64);
        rA[k] += __shfl_xor(rA[k], 16, 64);
        rA[k] += __shfl_xor(rA[k], 32, 64);
        rB[k] += __shfl_xor(rB[k], 8, 64);
        rB[k] += __shfl_xor(rB[k], 16, 64);
        rB[k] += __shfl_xor(rB[k], 32, 64);
        rC[k] += __shfl_xor(rC[k], 8, 64);
        rC[k] += __shfl_xor(rC[k], 16, 64);
        rC[k] += __shfl_xor(rC[k], 32, 64);
        rD[k] += __shfl_xor(rD[k], 8, 64);
        rD[k] += __shfl_xor(rD[k], 16, 64);
        rD[k] += __shfl_xor(rD[k], 32, 64);
    }
    if (slot == 0) {
        #pragma unroll
        for (int k = 0; k < 8; ++k) {
            sh[w * 4 + 0][grp * 8 + k] = rA[k] * invA;
            sh[w * 4 + 1][grp * 8 + k] = rB[k] * invB;
            sh[w * 4 + 2][grp * 8 + k] = rC[k] * invC;
            sh[w * 4 + 3][grp * 8 + k] = rD[k] * invD;
        }
    }
    __syncthreads();
    if (threadIdx.x < HID) {             // grouped poolA atomics (batch sorted)
        int j = threadIdx.x;
        int cur = batch[base];
        float v = sh[0][j];
        #pragma unroll
        for (int r = 1; r < 16; ++r) {
            int g = batch[base + r];
            float val = sh[r][j];
            if (g == cur) v += val;
            else { atomicAdd(&poolA[cur * HID + j], v); cur = g; v = val; }
        }
        atomicAdd(&poolA[cur * HID + j], v);
    }
}

// K5: readout. xg = (poolA@Wl2 + poolH@Wr2)/cnt + b2, then 64->32->1 MLP.
__global__ void mlp_kernel(const float* __restrict__ poolA,
                           const float* __restrict__ poolH,
                           const int* __restrict__ batch,
                           const float* __restrict__ Wl2,
                           const float* __restrict__ Wr2,
                           const float* __restrict__ b2,
                           const float* __restrict__ Wm1,
                           const float* __restrict__ bm1,
                           const float* __restrict__ Wm2,
                           const float* __restrict__ bm2,
                           float* __restrict__ out) {
    __shared__ float spA[4][HID], spH[4][HID], sx[4][HID];
    int t = blockIdx.x * blockDim.x + threadIdx.x;
    int g = t >> 6;
    int j = t & 63;
    int w = threadIdx.x >> 6;
    if (g >= N_GRAPHS) return;
    int lo = 0, hi = N_NODES;
    while (lo < hi) { int m = (lo + hi) >> 1; if (batch[m] < g) lo = m + 1; else hi = m; }
    int start = lo;
    lo = 0; hi = N_NODES;
    while (lo < hi) { int m = (lo + hi) >> 1; if (batch[m] < g + 1) lo = m + 1; else hi = m; }
    int cntg = lo - start;
    float inv = 1.0f / fmaxf((float)cntg, 1.0f);
    spA[w][j] = poolA[g * HID + j];
    spH[w][j] = poolH[g * HID + j];
    float acc = 0.0f;
    #pragma unroll 8
    for (int k = 0; k < HID; ++k)
        acc += spA[w][k] * Wl2[k * HID + j] + spH[w][k] * Wr2[k * HID + j];
    sx[w][j] = acc * inv + b2[j];
    if (j < 32) {
        float a = bm1[j];
        #pragma unroll 8
        for (int k = 0; k < HID; ++k)
            a += sx[w][k] * Wm1[k * 32 + j];
        float r = fmaxf(a, 0.0f) * Wm2[j];
        #pragma unroll
        for (int off = 16; off > 0; off >>= 1)
            r += __shfl_down(r, off, 32);
        if (j == 0)
            out[g] = 1.0f / (1.0f + expf(-(r + bm2[0])));
    }
}

extern "C" void kernel_launch(void* const* d_in, const int* in_sizes, int n_in,
                              void* d_out, int out_size, void* d_ws, size_t ws_size,
                              hipStream_t stream) {
    const float* x    = (const float*)d_in[0];
    const int*   ei   = (const int*)d_in[1];
    // d_in[2] = edge_attr (all zeros, unused)
    const int*   batch= (const int*)d_in[3];
    const float* Wl1  = (const float*)d_in[4];
    const float* Wr1  = (const float*)d_in[5];
    const float* b1   = (const float*)d_in[6];
    const float* Wl2  = (const float*)d_in[7];
    const float* Wr2  = (const float*)d_in[8];
    const float* b2   = (const float*)d_in[9];
    const float* Wm1  = (const float*)d_in[10];
    const float* bm1  = (const float*)d_in[11];
    const float* Wm2  = (const float*)d_in[12];
    const float* bm2  = (const float*)d_in[13];
    float* out = (float*)d_out;

    int*   wsi = (int*)d_ws;
    float* wsf = (float*)d_ws;
    float*  poolA  = wsf;
    float*  poolH  = wsf + 64000;
    int*    gcur   = wsi + 128000;
    int2*   rowcnt = (int2*)(wsi + 128200);
    int*    col    = wsi + 328200;
    int*    ebuf   = wsi + 2736648;
    uint32* x8b    = (uint32*)(wsi + 5145096);
    uint32* h1b    = (uint32*)(wsi + 5545096);

    {   int bl = (NZERO / 4 + 255) / 256;                    // 126
        zero_kernel<<<bl, 256, 0, stream>>>((float4*)d_ws);
    }
    {   int bl = (N_EDGES + CHUNK - 1) / CHUNK;              // 391
        pad_part_kernel<<<bl, 256, 0, stream>>>(x, ei, gcur, ebuf, x8b);
    }
    build_csr_kernel<<<NBUCK, 1024, 0, stream>>>(ebuf, gcur, rowcnt, col);
    {   int th = 256, bl = N_NODES / NPB;                    // 3125
        agg_l1_kernel<<<bl, th, 0, stream>>>(x, x8b, rowcnt, col, Wl1, Wr1, b1,
                                             batch, h1b, poolH);
    }
    {   int th = 256, bl = N_NODES / 16;                     // 6250
        gather2_kernel<<<bl, th, 0, stream>>>(h1b, rowcnt, col, batch, poolA);
    }
    {   int th = 256, bl = (N_GRAPHS * 64) / th;             // 250
        mlp_kernel<<<bl, th, 0, stream>>>(poolA, poolH, batch,
                                          Wl2, Wr2, b2, Wm1, bm1, Wm2, bm2, out);
    }
}

// Round 25
// 125.424 us; speedup vs baseline: 1.3173x; 1.3173x over previous
//
#include <hip/hip_runtime.h>
#include <math.h>

#define N_NODES  100000
#define N_EDGES  1600000
#define N_GRAPHS 1000
#define F_IN     9
#define HID      64
#define NBUCK    196    // ceil(N_NODES / 512), bucket = dst >> 9
#define BCAP     12288  // fixed capacity per bucket (mean 8163, +45 sigma)
#define CHUNK    4096   // edges per partition block
#define NZERO    128200 // words to zero (poolA + poolH + gcur)
#define NPB      32     // nodes per agg_l1 block

typedef unsigned int uint32;
typedef float v2f __attribute__((ext_vector_type(2)));

// ---------------------------------------------------------------------------
// Workspace layout (4-byte words):
//   [0,        64000)    poolA  (float) -- zeroed (graph-sum of mean-agg(h1))
//   [64000,    128000)   poolH  (float) -- zeroed (graph-sum of h1)
//   [128000,   128196)   gcur   (int)   -- zeroed (bucket fill cursors)
//   ZERO region = [0, 128200)  (custom zero_kernel; the ~44us fillBuffer in
//   the profile is the HARNESS's one-time d_ws poison, not in the replay path)
//   [128200,   328200)   rowcnt (int2 per node: {col start, degree})
//   [328200,   2736648)  col    (int, NBUCK*BCAP)
//   [2736648,  5145096)  ebuf   (packed int: src | ldst<<17, NBUCK*BCAP)
//   [5145096,  5545096)  x8b    (fp8 e4m3, N*16 feats = 4 words/node)
//   [5545096,  7145096)  h1b    (fp8 e4m3, row-major, N*64 feats = 16 words/node)
// Total 7.15M words = 28.6 MB.
// ---------------------------------------------------------------------------

// HW fp8 e4m3 converters (gfx950 OCP e4m3fn; roundtrip-consistent)
__device__ __forceinline__ uint32 pk_lo(float a, float b, uint32 old) {
    return (uint32)__builtin_amdgcn_cvt_pk_fp8_f32(a, b, (int)old, false);
}
__device__ __forceinline__ uint32 pk_hi(float a, float b, uint32 old) {
    return (uint32)__builtin_amdgcn_cvt_pk_fp8_f32(a, b, (int)old, true);
}
__device__ __forceinline__ float bfl(uint32 w) { return __uint_as_float(w << 16); }
__device__ __forceinline__ float bfh(uint32 w) { return __uint_as_float(w & 0xffff0000u); }
__device__ __forceinline__ uint32 f2bf1(float f) {
    uint32 u = __float_as_uint(f);
    u += 0x7fffu + ((u >> 16) & 1u);           // round-to-nearest-even
    return u >> 16;
}
__device__ __forceinline__ uint32 bfpair(float lo, float hi) {
    return f2bf1(lo) | (f2bf1(hi) << 16);
}

// accumulate two fp8 rows (8 feats of each) into 4 v2f accumulators
__device__ __forceinline__ void acc2(const uint32* __restrict__ hb, int c0, int c1,
                                     v2f& a0, v2f& a1, v2f& a2, v2f& a3) {
    uint2 d0 = *reinterpret_cast<const uint2*>(hb + (size_t)c0 * 16);
    uint2 d1 = *reinterpret_cast<const uint2*>(hb + (size_t)c1 * 16);
    a0 += __builtin_amdgcn_cvt_pk_f32_fp8((int)d0.x, false);
    a1 += __builtin_amdgcn_cvt_pk_f32_fp8((int)d0.x, true);
    a2 += __builtin_amdgcn_cvt_pk_f32_fp8((int)d0.y, false);
    a3 += __builtin_amdgcn_cvt_pk_f32_fp8((int)d0.y, true);
    a0 += __builtin_amdgcn_cvt_pk_f32_fp8((int)d1.x, false);
    a1 += __builtin_amdgcn_cvt_pk_f32_fp8((int)d1.x, true);
    a2 += __builtin_amdgcn_cvt_pk_f32_fp8((int)d1.y, false);
    a3 += __builtin_amdgcn_cvt_pk_f32_fp8((int)d1.y, true);
}
__device__ __forceinline__ void acc1(const uint32* __restrict__ hb, int c0,
                                     v2f& a0, v2f& a1, v2f& a2, v2f& a3) {
    uint2 d0 = *reinterpret_cast<const uint2*>(hb + (size_t)c0 * 16);
    a0 += __builtin_amdgcn_cvt_pk_f32_fp8((int)d0.x, false);
    a1 += __builtin_amdgcn_cvt_pk_f32_fp8((int)d0.x, true);
    a2 += __builtin_amdgcn_cvt_pk_f32_fp8((int)d0.y, false);
    a3 += __builtin_amdgcn_cvt_pk_f32_fp8((int)d0.y, true);
}

// K0: zero the accumulator region
__global__ __launch_bounds__(256) void zero_kernel(float4* __restrict__ ws) {
    int i = blockIdx.x * 256 + threadIdx.x;          // 126 blocks x 256 x 4 words
    if (i * 4 < NZERO)
        ws[i] = make_float4(0.f, 0.f, 0.f, 0.f);
}

// K1: encode x -> x8b (fp8) AND fixed-capacity bucket partition (packed entries)
__global__ __launch_bounds__(256) void pad_part_kernel(const float* __restrict__ x,
                                                       const int* __restrict__ ei,
                                                       int* __restrict__ gcur,
                                                       int* __restrict__ ebuf,
                                                       uint32* __restrict__ x8b) {
    __shared__ int lcnt[NBUCK], lbase[NBUCK];
    int tid = threadIdx.x;

    // --- encode phase: one node per thread (391*256 = 100096 >= N) ---
    int n = blockIdx.x * 256 + tid;
    if (n < N_NODES) {
        uint32 w[4];
        #pragma unroll
        for (int p = 0; p < 4; ++p) {
            float v0 = (4 * p + 0 < F_IN) ? x[(size_t)n * F_IN + 4 * p + 0] : 0.0f;
            float v1 = (4 * p + 1 < F_IN) ? x[(size_t)n * F_IN + 4 * p + 1] : 0.0f;
            float v2 = (4 * p + 2 < F_IN) ? x[(size_t)n * F_IN + 4 * p + 2] : 0.0f;
            float v3 = (4 * p + 3 < F_IN) ? x[(size_t)n * F_IN + 4 * p + 3] : 0.0f;
            w[p] = pk_hi(v2, v3, pk_lo(v0, v1, 0u));
        }
        *reinterpret_cast<uint4*>(&x8b[(size_t)n * 4]) =
            make_uint4(w[0], w[1], w[2], w[3]);
    }

    // --- partition phase: block-aggregated reservation into fixed buckets ---
    for (int i = tid; i < NBUCK; i += 256) lcnt[i] = 0;
    __syncthreads();
    int e0 = blockIdx.x * CHUNK;
    int e1 = e0 + CHUNK; if (e1 > N_EDGES) e1 = N_EDGES;
    for (int e = e0 + tid; e < e1; e += 256)
        atomicAdd(&lcnt[ei[N_EDGES + e] >> 9], 1);
    __syncthreads();
    for (int i = tid; i < NBUCK; i += 256)
        lbase[i] = atomicAdd(&gcur[i], lcnt[i]);
    __syncthreads();
    for (int i = tid; i < NBUCK; i += 256) lcnt[i] = 0;
    __syncthreads();
    for (int e = e0 + tid; e < e1; e += 256) {
        int src = ei[e];
        int dst = ei[N_EDGES + e];
        int b = dst >> 9;
        int pos = lbase[b] + atomicAdd(&lcnt[b], 1);
        if (pos < BCAP)
            ebuf[(size_t)b * BCAP + pos] = src | ((dst & 511) << 17);
    }
}

// K2: per-bucket CSR build (512 nodes/bucket, 1024 threads), count+scan+place
__global__ __launch_bounds__(1024) void build_csr_kernel(const int* __restrict__ ebuf,
                                                         const int* __restrict__ gcur,
                                                         int2* __restrict__ rowcnt,
                                                         int* __restrict__ col) {
    __shared__ int cnt[512];
    __shared__ int cur[512];
    __shared__ int wsum[8];
    int b = blockIdx.x;
    int n0 = b << 9;
    int tid = threadIdx.x;
    int ec = gcur[b]; if (ec > BCAP) ec = BCAP;
    size_t base = (size_t)b * BCAP;
    if (tid < 512) cnt[tid] = 0;
    __syncthreads();
    for (int e = tid; e < ec; e += 1024)
        atomicAdd(&cnt[(uint32)ebuf[base + e] >> 17], 1);
    __syncthreads();
    int v = 0, s = 0;
    int lane = tid & 63, wid = tid >> 6;
    if (tid < 512) {                     // waves 0..7 scan the 512 counts
        v = cnt[tid];
        s = v;
        #pragma unroll
        for (int off = 1; off < 64; off <<= 1) {
            int u = __shfl_up(s, off, 64);
            if (lane >= off) s += u;
        }
        if (lane == 63) wsum[wid] = s;
    }
    __syncthreads();
    if (tid < 512) {
        int add = 0;
        for (int w = 0; w < wid; ++w) add += wsum[w];
        int off_ex = s - v + add;        // exclusive scan within bucket
        int n = n0 + tid;
        if (n < N_NODES) rowcnt[n] = make_int2((int)base + off_ex, v);
        cur[tid] = off_ex;
    }
    __syncthreads();
    for (int e = tid; e < ec; e += 1024) {
        int pv = ebuf[base + e];
        int pos = atomicAdd(&cur[(uint32)pv >> 17], 1);
        col[base + pos] = pv & 0x1FFFF;
    }
}

// K3: fused layer-1 aggregation + dense + poolH. 32 nodes/block, 3125 blocks.
__global__ __launch_bounds__(256) void agg_l1_kernel(const float* __restrict__ x,
                                                     const uint32* __restrict__ x8b,
                                                     const int2* __restrict__ rowcnt,
                                                     const int* __restrict__ col,
                                                     const float* __restrict__ Wl1,
                                                     const float* __restrict__ Wr1,
                                                     const float* __restrict__ b1,
                                                     const int* __restrict__ batch,
                                                     uint32* __restrict__ h1b,
                                                     float* __restrict__ poolH) {
    __shared__ float  w1s[F_IN * 128];   // [f][ Wl1 | Wr1 ]
    __shared__ float  bs[HID];
    __shared__ float  ss[NPB * 20];      // mean-agg tile
    __shared__ float  xs[NPB * 10];      // x tile (f32, exact)
    __shared__ uint32 hsp[NPB * 33];     // h1 rows, bf16-packed
    int tid = threadIdx.x;
    int n0 = blockIdx.x * NPB;           // 3125 * 32 = 100000 exactly
    for (int i = tid; i < F_IN * HID; i += 256) {
        int f = i >> 6, j = i & 63;
        w1s[f * 128 + j]      = Wl1[i];
        w1s[f * 128 + 64 + j] = Wr1[i];
    }
    if (tid < HID) bs[tid] = b1[tid];
    for (int i = tid; i < NPB * F_IN; i += 256) {
        int r = i / F_IN, f = i - r * F_IN;
        xs[r * 10 + f] = x[(size_t)(n0 + r) * F_IN + f];
    }

    // gather phase: node r = tid>>3; slot s = (tid>>2)&1; dword q = tid&3
    {
        int r = tid >> 3, s = (tid >> 2) & 1, q = tid & 3;
        int2 rc = rowcnt[n0 + r];
        int deg = rc.y;
        v2f a01 = {0.f, 0.f}, a23 = {0.f, 0.f};
        int i = s;
        for (; i + 6 < deg; i += 8) {    // 4 edges of this slot in flight
            int c0 = col[rc.x + i];
            int c1 = col[rc.x + i + 2];
            int c2 = col[rc.x + i + 4];
            int c3 = col[rc.x + i + 6];
            uint32 d0 = x8b[(size_t)c0 * 4 + q];
            uint32 d1 = x8b[(size_t)c1 * 4 + q];
            uint32 d2 = x8b[(size_t)c2 * 4 + q];
            uint32 d3 = x8b[(size_t)c3 * 4 + q];
            a01 += __builtin_amdgcn_cvt_pk_f32_fp8((int)d0, false);
            a23 += __builtin_amdgcn_cvt_pk_f32_fp8((int)d0, true);
            a01 += __builtin_amdgcn_cvt_pk_f32_fp8((int)d1, false);
            a23 += __builtin_amdgcn_cvt_pk_f32_fp8((int)d1, true);
            a01 += __builtin_amdgcn_cvt_pk_f32_fp8((int)d2, false);
            a23 += __builtin_amdgcn_cvt_pk_f32_fp8((int)d2, true);
            a01 += __builtin_amdgcn_cvt_pk_f32_fp8((int)d3, false);
            a23 += __builtin_amdgcn_cvt_pk_f32_fp8((int)d3, true);
        }
        for (; i < deg; i += 2) {
            uint32 d0 = x8b[(size_t)col[rc.x + i] * 4 + q];
            a01 += __builtin_amdgcn_cvt_pk_f32_fp8((int)d0, false);
            a23 += __builtin_amdgcn_cvt_pk_f32_fp8((int)d0, true);
        }
        float r4[4] = {a01[0], a01[1], a23[0], a23[1]};
        #pragma unroll
        for (int k = 0; k < 4; ++k)      // combine the 2 slots (lane bit 2)
            r4[k] += __shfl_xor(r4[k], 4, 64);
        if (s == 0) {
            float inv = 1.0f / fmaxf((float)deg, 1.0f);
            *reinterpret_cast<float4*>(&ss[r * 20 + q * 4]) =
                make_float4(r4[0] * inv, r4[1] * inv, r4[2] * inv, r4[3] * inv);
        }
    }
    __syncthreads();

    // dense phase: node r = tid>>3, col-group cg = tid&7 (8 feats each)
    int r = tid >> 3, cg = tid & 7, k0 = cg * 8;
    float h[8];
    #pragma unroll
    for (int kk = 0; kk < 8; ++kk) {
        int k = k0 + kk;
        float v = bs[k];
        #pragma unroll
        for (int f = 0; f < F_IN; ++f)
            v += ss[r * 20 + f] * w1s[f * 128 + k]
               + xs[r * 10 + f] * w1s[f * 128 + 64 + k];
        h[kk] = fmaxf(v, 0.0f);
    }
    int n = n0 + r;
    {   // fp8 encode: 8 feats -> 2 words
        uint32 w0 = pk_hi(h[2], h[3], pk_lo(h[0], h[1], 0u));
        uint32 w1 = pk_hi(h[6], h[7], pk_lo(h[4], h[5], 0u));
        *reinterpret_cast<uint2*>(&h1b[(size_t)n * 16 + cg * 2]) =
            make_uint2(w0, w1);
    }
    {   // bf16-pack into hsp for the pool tail
        hsp[r * 33 + cg * 4 + 0] = bfpair(h[0], h[1]);
        hsp[r * 33 + cg * 4 + 1] = bfpair(h[2], h[3]);
        hsp[r * 33 + cg * 4 + 2] = bfpair(h[4], h[5]);
        hsp[r * 33 + cg * 4 + 3] = bfpair(h[6], h[7]);
    }
    __syncthreads();
    if (tid < HID) {                     // grouped poolH atomics (batch sorted)
        int j = tid;
        int wsel = j >> 1;
        bool hi = (j & 1) != 0;
        int cur = batch[n0];
        uint32 w0 = hsp[wsel];
        float v = hi ? bfh(w0) : bfl(w0);
        for (int rr = 1; rr < NPB; ++rr) {
            int g = batch[n0 + rr];
            uint32 wr = hsp[rr * 33 + wsel];
            float val = hi ? bfh(wr) : bfl(wr);
            if (g == cur) v += val;
            else { atomicAdd(&poolH[cur * HID + j], v); cur = g; v = val; }
        }
        atomicAdd(&poolH[cur * HID + j], v);
    }
}

// K4: layer-2 gather, 2 interleaved nodes per wave (independent chains, 4 rows
// in flight). block = 4 waves = 8 nodes; 12500 blocks; grouped pool atomics.
__global__ __launch_bounds__(256) void gather2_kernel(const uint32* __restrict__ h1b,
                                                      const int2* __restrict__ rowcnt,
                                                      const int* __restrict__ col,
                                                      const int* __restrict__ batch,
                                                      float* __restrict__ poolA) {
    __shared__ float sh[8][HID];
    int w = threadIdx.x >> 6;
    int lane = threadIdx.x & 63;
    int slot = lane >> 3;                // 8 edge slots
    int grp  = lane & 7;                 // 8 feature groups x 8 fp8
    int base = blockIdx.x * 8;           // 12500 * 8 = 100000 exactly
    int nA = base + w * 2;
    int nB = nA + 1;
    int2 rcA = rowcnt[nA];
    int2 rcB = rowcnt[nB];
    const uint32* hb = h1b + grp * 2;
    v2f aA0 = {0.f,0.f}, aA1 = {0.f,0.f}, aA2 = {0.f,0.f}, aA3 = {0.f,0.f};
    v2f aB0 = {0.f,0.f}, aB1 = {0.f,0.f}, aB2 = {0.f,0.f}, aB3 = {0.f,0.f};
    int iA = rcA.x + slot, endA = rcA.x + rcA.y;
    int iB = rcB.x + slot, endB = rcB.x + rcB.y;
    // fused main loop: col loads for A and B, then 4 rows in flight
    while (iA + 8 < endA && iB + 8 < endB) {
        int cA0 = col[iA], cA1 = col[iA + 8];
        int cB0 = col[iB], cB1 = col[iB + 8];
        acc2(hb, cA0, cA1, aA0, aA1, aA2, aA3);
        acc2(hb, cB0, cB1, aB0, aB1, aB2, aB3);
        iA += 16; iB += 16;
    }
    for (; iA + 8 < endA; iA += 16) {
        int c0 = col[iA], c1 = col[iA + 8];
        acc2(hb, c0, c1, aA0, aA1, aA2, aA3);
    }
    if (iA < endA) acc1(hb, col[iA], aA0, aA1, aA2, aA3);
    for (; iB + 8 < endB; iB += 16) {
        int c0 = col[iB], c1 = col[iB + 8];
        acc2(hb, c0, c1, aB0, aB1, aB2, aB3);
    }
    if (iB < endB) acc1(hb, col[iB], aB0, aB1, aB2, aB3);

    float rA[8] = {aA0[0], aA0[1], aA1[0], aA1[1], aA2[0], aA2[1], aA3[0], aA3[1]};
    float rB[8] = {aB0[0], aB0[1], aB1[0], aB1[1], aB2[0], aB2[1], aB3[0], aB3[1]};
    float invA = 1.0f / fmaxf((float)rcA.y, 1.0f);
    float invB = 1.0f / fmaxf((float)rcB.y, 1.0f);
    #pragma unroll
    for (int k = 0; k < 8; ++k) {        // reduce across 8 slots (lane bits 3..5)
        rA[k] += __shfl_xor(rA[k], 8, 64);
        rA[k] += __shfl_xor(rA[k], 16, 64);
        rA[k] += __shfl_xor(rA[k], 32, 64);
        rB[k] += __shfl_xor(rB[k], 8, 64);
        rB[k] += __shfl_xor(rB[k], 16, 64);
        rB[k] += __shfl_xor(rB[k], 32, 64);
    }
    if (slot == 0) {
        #pragma unroll
        for (int k = 0; k < 8; ++k) {
            sh[w * 2 + 0][grp * 8 + k] = rA[k] * invA;
            sh[w * 2 + 1][grp * 8 + k] = rB[k] * invB;
        }
    }
    __syncthreads();
    if (threadIdx.x < HID) {             // grouped poolA atomics (batch sorted)
        int j = threadIdx.x;
        int cur = batch[base];
        float v = sh[0][j];
        #pragma unroll
        for (int r = 1; r < 8; ++r) {
            int g = batch[base + r];
            float val = sh[r][j];
            if (g == cur) v += val;
            else { atomicAdd(&poolA[cur * HID + j], v); cur = g; v = val; }
        }
        atomicAdd(&poolA[cur * HID + j], v);
    }
}

// K5: readout. xg = (poolA@Wl2 + poolH@Wr2)/cnt + b2, then 64->32->1 MLP.
__global__ void mlp_kernel(const float* __restrict__ poolA,
                           const float* __restrict__ poolH,
                           const int* __restrict__ batch,
                           const float* __restrict__ Wl2,
                           const float* __restrict__ Wr2,
                           const float* __restrict__ b2,
                           const float* __restrict__ Wm1,
                           const float* __restrict__ bm1,
                           const float* __restrict__ Wm2,
                           const float* __restrict__ bm2,
                           float* __restrict__ out) {
    __shared__ float spA[4][HID], spH[4][HID], sx[4][HID];
    int t = blockIdx.x * blockDim.x + threadIdx.x;
    int g = t >> 6;
    int j = t & 63;
    int w = threadIdx.x >> 6;
    if (g >= N_GRAPHS) return;
    int lo = 0, hi = N_NODES;
    while (lo < hi) { int m = (lo + hi) >> 1; if (batch[m] < g) lo = m + 1; else hi = m; }
    int start = lo;
    lo = 0; hi = N_NODES;
    while (lo < hi) { int m = (lo + hi) >> 1; if (batch[m] < g + 1) lo = m + 1; else hi = m; }
    int cntg = lo - start;
    float inv = 1.0f / fmaxf((float)cntg, 1.0f);
    spA[w][j] = poolA[g * HID + j];
    spH[w][j] = poolH[g * HID + j];
    float acc = 0.0f;
    #pragma unroll 8
    for (int k = 0; k < HID; ++k)
        acc += spA[w][k] * Wl2[k * HID + j] + spH[w][k] * Wr2[k * HID + j];
    sx[w][j] = acc * inv + b2[j];
    if (j < 32) {
        float a = bm1[j];
        #pragma unroll 8
        for (int k = 0; k < HID; ++k)
            a += sx[w][k] * Wm1[k * 32 + j];
        float r = fmaxf(a, 0.0f) * Wm2[j];
        #pragma unroll
        for (int off = 16; off > 0; off >>= 1)
            r += __shfl_down(r, off, 32);
        if (j == 0)
            out[g] = 1.0f / (1.0f + expf(-(r + bm2[0])));
    }
}

extern "C" void kernel_launch(void* const* d_in, const int* in_sizes, int n_in,
                              void* d_out, int out_size, void* d_ws, size_t ws_size,
                              hipStream_t stream) {
    const float* x    = (const float*)d_in[0];
    const int*   ei   = (const int*)d_in[1];
    // d_in[2] = edge_attr (all zeros, unused)
    const int*   batch= (const int*)d_in[3];
    const float* Wl1  = (const float*)d_in[4];
    const float* Wr1  = (const float*)d_in[5];
    const float* b1   = (const float*)d_in[6];
    const float* Wl2  = (const float*)d_in[7];
    const float* Wr2  = (const float*)d_in[8];
    const float* b2   = (const float*)d_in[9];
    const float* Wm1  = (const float*)d_in[10];
    const float* bm1  = (const float*)d_in[11];
    const float* Wm2  = (const float*)d_in[12];
    const float* bm2  = (const float*)d_in[13];
    float* out = (float*)d_out;

    int*   wsi = (int*)d_ws;
    float* wsf = (float*)d_ws;
    float*  poolA  = wsf;
    float*  poolH  = wsf + 64000;
    int*    gcur   = wsi + 128000;
    int2*   rowcnt = (int2*)(wsi + 128200);
    int*    col    = wsi + 328200;
    int*    ebuf   = wsi + 2736648;
    uint32* x8b    = (uint32*)(wsi + 5145096);
    uint32* h1b    = (uint32*)(wsi + 5545096);

    {   int bl = (NZERO / 4 + 255) / 256;                    // 126
        zero_kernel<<<bl, 256, 0, stream>>>((float4*)d_ws);
    }
    {   int bl = (N_EDGES + CHUNK - 1) / CHUNK;              // 391
        pad_part_kernel<<<bl, 256, 0, stream>>>(x, ei, gcur, ebuf, x8b);
    }
    build_csr_kernel<<<NBUCK, 1024, 0, stream>>>(ebuf, gcur, rowcnt, col);
    {   int th = 256, bl = N_NODES / NPB;                    // 3125
        agg_l1_kernel<<<bl, th, 0, stream>>>(x, x8b, rowcnt, col, Wl1, Wr1, b1,
                                             batch, h1b, poolH);
    }
    {   int th = 256, bl = N_NODES / 8;                      // 12500
        gather2_kernel<<<bl, th, 0, stream>>>(h1b, rowcnt, col, batch, poolA);
    }
    {   int th = 256, bl = (N_GRAPHS * 64) / th;             // 250
        mlp_kernel<<<bl, th, 0, stream>>>(poolA, poolH, batch,
                                          Wl2, Wr2, b2, Wm1, bm1, Wm2, bm2, out);
    }
}